// Round 18
// baseline (446.262 us; speedup 1.0000x reference)
//
#include <hip/hip_runtime.h>

// ---------------------------------------------------------------------------
// Kimi MLA attention block, MI355X (gfx950).  Round 18 = round-17 (verified
// 445.7us) + fusion of rmsnorm/rope_k/rope_q into ONE kernel (normrope_k):
// the three parts touch disjoint column ranges of qc (rmsnorm reads
// 6144..6655 -> ckvn; rope_k reads 6656..6719 -> kr; rope_q rewrites
// h*192+128..191 in place, all < 6144), so no intra-kernel hazards.
// Saves two kernel launches. All compute kernels byte-identical to r17.
// ---------------------------------------------------------------------------

typedef __bf16 bf16x8 __attribute__((ext_vector_type(8)));
typedef float f32x4 __attribute__((ext_vector_type(4)));

#define SEQLEN 2048
#define NH 32
#define QH 192
#define QCN 6912  // combined q (6144) + ckv (640 used, 768 padded) columns
#define KVN 8192  // NH*256
#define HID 4096

#define AS1 __attribute__((address_space(1)))
#define AS3 __attribute__((address_space(3)))

__device__ __forceinline__ unsigned short f2b(float f) {
  union { float f; unsigned int u; } x; x.f = f;
  unsigned int r = (x.u + 0x7FFFu + ((x.u >> 16) & 1u)) >> 16;
  return (unsigned short)r;
}
__device__ __forceinline__ float b2f(unsigned short b) {
  union { unsigned int u; float f; } x; x.u = ((unsigned int)b) << 16;
  return x.f;
}

// ---- elementwise f32 -> bf16 (vectorized) ----
__global__ __launch_bounds__(256) void convk(const float* __restrict__ in,
                                             unsigned short* __restrict__ out,
                                             int n4) {
  int i = blockIdx.x * 256 + threadIdx.x;
  if (i < n4) {
    float4 v = ((const float4*)in)[i];
    ushort4 o;
    o.x = f2b(v.x); o.y = f2b(v.y); o.z = f2b(v.z); o.w = f2b(v.w);
    ((ushort4*)out)[i] = o;
  }
}

// ---- transpose+convert+scale: out[c][r] = bf16(scl*in[r][c]) ----
__global__ __launch_bounds__(256) void tconv(const float* __restrict__ in,
                                             unsigned short* __restrict__ out,
                                             int R, int Cin, int Cp, float scl) {
  __shared__ float t[64][65];
  const int r0 = blockIdx.x * 64, c0 = blockIdx.y * 64;
  const int tid = threadIdx.x;
#pragma unroll
  for (int i = 0; i < 16; ++i) {
    int idx = tid + i * 256;
    int rr = idx >> 6, cc = idx & 63;
    int c = c0 + cc;
    t[rr][cc] = (c < Cin) ? in[(size_t)(r0 + rr) * Cin + c] * scl : 0.f;
  }
  __syncthreads();
#pragma unroll
  for (int i = 0; i < 16; ++i) {
    int idx = tid + i * 256;
    int cc = idx >> 6, rr = idx & 63;
    out[(size_t)(c0 + cc) * R + (r0 + rr)] = f2b(t[rr][cc]);
  }
}

// ---- MFMA quadrant helper (all register indices compile-time; rule #20) ----
template <int MH, int MHALF, int PAIR>
__device__ __forceinline__ void mmaq(f32x4 (*acc)[4], const bf16x8* aR, const bf16x8* bX) {
  __builtin_amdgcn_s_setprio(1);
#pragma unroll
  for (int i2 = 0; i2 < MH; ++i2)
#pragma unroll
    for (int kk = 0; kk < 2; ++kk)
#pragma unroll
      for (int j = 0; j < 2; ++j)
        acc[MHALF * MH + i2][PAIR * 2 + j] = __builtin_amdgcn_mfma_f32_16x16x32_bf16(
            aR[i2 * 2 + kk], bX[j * 2 + kk], acc[MHALF * MH + i2][PAIR * 2 + j], 0, 0, 0);
  __builtin_amdgcn_s_setprio(0);
}

#define PH_SYNC()                                        \
  __builtin_amdgcn_s_barrier();                          \
  asm volatile("s_waitcnt lgkmcnt(0)" ::: "memory");     \
  __builtin_amdgcn_sched_barrier(0)
#define PH_END() __builtin_amdgcn_s_barrier()

// ---- BMx256 8-phase GEMM: C[M,N] = A[M,K] * B[N,K]^T, bf16 in, fp32 acc ----
// LDS half-tile = [rows][64] bf16 row-major, slot-XOR: unit u holds
// G[row = u>>3][slot = (u&7) ^ ((u>>3)&7)]. Staging covers whole 128B rows
// (coalesced); frag read slot = (kk*4+(l>>4)) ^ (l&7) (conflict-free).
// 8-phase schedule, counted vmcnt(4) at p4/p8, two barriers/phase. [r13]
template <int BM, typename OutT>
__global__ __launch_bounds__(512, 2) void gemm8p(const unsigned short* __restrict__ A,
                                                 const unsigned short* __restrict__ B,
                                                 OutT* __restrict__ C,
                                                 int M, int N, int K) {
  constexpr int MF = BM / 32;
  constexpr int MH = MF / 2;
  constexpr int ARND = BM / 128;
  __shared__ __align__(16) unsigned short As[2][2][BM * 32];  // [buf][half]
  __shared__ __align__(16) unsigned short Bs[2][2][8192];

  const int tid = threadIdx.x;
  const int lane = tid & 63;
  const int w = tid >> 6;
  const int wr = w >> 2, wc = w & 3;
  const int l15 = lane & 15, lg = lane >> 4;
  const int l7 = lane & 7;
  const int ntn = N >> 8;
  // XCD-row swizzle (bijective for nbm % 8 == 0; here nbm in {8,16})
  const int g = blockIdx.x & 7, s = blockIdx.x >> 3;
  const int bn = s % ntn;
  const int bm = g + 8 * (s / ntn);
  const int m0 = bm * BM, n0 = bn << 8;

  auto stA = [&](int t, int h) {
    const int buf = t & 1, k0 = t << 6;
#pragma unroll
    for (int r = 0; r < ARND; ++r) {
      int u = r * 512 + tid;
      int row = u >> 3;
      int sslot = (u & 7) ^ (row & 7);
      __builtin_amdgcn_global_load_lds(
          (const AS1 void*)(A + (size_t)(m0 + h * (BM / 2) + row) * K + (k0 + sslot * 8)),
          (AS3 void*)(&As[buf][h][u * 8]), 16, 0, 0);
    }
  };
  auto stB = [&](int t, int h) {
    const int buf = t & 1, k0 = t << 6;
#pragma unroll
    for (int r = 0; r < 2; ++r) {
      int u = r * 512 + tid;
      int row = u >> 3;
      int sslot = (u & 7) ^ (row & 7);
      __builtin_amdgcn_global_load_lds(
          (const AS1 void*)(B + (size_t)(n0 + h * 128 + row) * K + (k0 + sslot * 8)),
          (AS3 void*)(&Bs[buf][h][u * 8]), 16, 0, 0);
    }
  };

  const f32x4 zero4 = {0.f, 0.f, 0.f, 0.f};
  f32x4 acc[MF][4];
#pragma unroll
  for (int i = 0; i < MF; ++i)
#pragma unroll
    for (int j = 0; j < 4; ++j) acc[i][j] = zero4;

  bf16x8 aR[MF], bA[4], bB[4];
  auto ldA = [&](int buf, int mhalf) {
#pragma unroll
    for (int i2 = 0; i2 < MH; ++i2)
#pragma unroll
      for (int kk = 0; kk < 2; ++kk) {
        int row = (mhalf * MH + i2) * 16 + l15;
        int slot = (kk * 4 + lg) ^ l7;
        aR[i2 * 2 + kk] = *(const bf16x8*)&As[buf][wr][(row * 8 + slot) * 8];
      }
  };
  auto ldB = [&](int buf, int pair, bf16x8* dst) {
#pragma unroll
    for (int j = 0; j < 2; ++j)
#pragma unroll
      for (int kk = 0; kk < 2; ++kk) {
        int row = (wc & 1) * 64 + (pair * 2 + j) * 16 + l15;
        int slot = (kk * 4 + lg) ^ l7;
        dst[j * 2 + kk] = *(const bf16x8*)&Bs[buf][wc >> 1][(row * 8 + slot) * 8];
      }
  };

  const int nk = K >> 6;
  const int ni = nk >> 1;

  stA(0, 0); stA(0, 1); stB(0, 0); stB(0, 1);
  stB(1, 0); stB(1, 1);
  asm volatile("s_waitcnt vmcnt(4)" ::: "memory");
  __builtin_amdgcn_s_barrier();

#pragma unroll 1
  for (int i = 0; i < ni; ++i) {
    const int tO = 2 * i + 1, tN = 2 * i + 2, tN1 = 2 * i + 3;
    const bool pfN = tN < nk, pfN1 = tN1 < nk;
    const bool steady = (i + 1 < ni);
    ldA(0, 0); ldB(0, 0, bA); stA(tO, 0);
    PH_SYNC(); mmaq<MH, 0, 0>(acc, aR, bA); PH_END();
    ldB(0, 1, bB); stA(tO, 1);
    PH_SYNC(); mmaq<MH, 0, 1>(acc, aR, bB); PH_END();
    ldA(0, 1); if (pfN) stB(tN, 0);
    PH_SYNC(); mmaq<MH, 1, 1>(acc, aR, bB); PH_END();
    if (pfN) stB(tN, 1);
    if (steady) { asm volatile("s_waitcnt vmcnt(4)" ::: "memory"); }
    else        { asm volatile("s_waitcnt vmcnt(0)" ::: "memory"); }
    PH_SYNC(); mmaq<MH, 1, 0>(acc, aR, bA); PH_END();
    ldA(1, 0); ldB(1, 0, bA); if (pfN) stA(tN, 0);
    PH_SYNC(); mmaq<MH, 0, 0>(acc, aR, bA); PH_END();
    ldB(1, 1, bB); if (pfN) stA(tN, 1);
    PH_SYNC(); mmaq<MH, 0, 1>(acc, aR, bB); PH_END();
    ldA(1, 1); if (pfN1) stB(tN1, 0);
    PH_SYNC(); mmaq<MH, 1, 1>(acc, aR, bB); PH_END();
    if (pfN1) stB(tN1, 1);
    if (steady) { asm volatile("s_waitcnt vmcnt(4)" ::: "memory"); }
    else        { asm volatile("s_waitcnt vmcnt(0)" ::: "memory"); }
    PH_SYNC(); mmaq<MH, 1, 0>(acc, aR, bA); PH_END();
  }

  const int r0 = m0 + wr * (BM / 2), c0 = n0 + wc * 64;
#pragma unroll
  for (int mf = 0; mf < MF; ++mf)
#pragma unroll
    for (int nf = 0; nf < 4; ++nf) {
      int r = r0 + mf * 16 + lg * 4;
      int c = c0 + nf * 16 + l15;
#pragma unroll
      for (int i = 0; i < 4; ++i) {
        float v = acc[mf][nf][i];
        if constexpr (sizeof(OutT) == 2)
          ((unsigned short*)C)[(size_t)(r + i) * N + c] = f2b(v);
        else
          ((float*)C)[(size_t)(r + i) * N + c] = v;
      }
    }
}

// ---- fused rmsnorm + rope_k + rope_q, one block per sequence row s ----
// part1: rmsnorm(qc[s][6144..6655]) -> ckvn[s][0..511]
// part2: rope_k(qc[s][6656..6719])  -> kr[s][0..63]
// part3: rope_q in place on qc[s][h*192+128 .. +191], h=0..31
// Disjoint ranges -> no hazards; one __syncthreads for the reduction only.
__global__ __launch_bounds__(256) void normrope_k(unsigned short* __restrict__ qc,
                                                  const float* __restrict__ w,
                                                  unsigned short* __restrict__ ckvn,
                                                  unsigned short* __restrict__ kr) {
  const int s = blockIdx.x;
  const int tid = threadIdx.x;
  // ---- part1: rmsnorm ----
  const unsigned short* row = qc + (size_t)s * QCN + 6144;
  float x0 = b2f(row[tid]), x1 = b2f(row[tid + 256]);
  float ss = x0 * x0 + x1 * x1;
#pragma unroll
  for (int o = 1; o < 64; o <<= 1) ss += __shfl_xor(ss, o, 64);
  __shared__ float red[4];
  if ((tid & 63) == 0) red[tid >> 6] = ss;
  __syncthreads();
  float rs = rsqrtf((red[0] + red[1] + red[2] + red[3]) * (1.f / 512.f) + 1e-6f);
  ckvn[(size_t)s * 512 + tid] = f2b(w[tid] * x0 * rs);
  ckvn[(size_t)s * 512 + tid + 256] = f2b(w[tid + 256] * x1 * rs);

  // ---- part2: rope_k (threads 0..31) ----
  if (tid < 32) {
    int i = tid;
    float inv = exp2f(-(float)i * 0.4152410118609203f);
    float ang = (float)s * inv;
    float c = cosf(ang), sn = sinf(ang);
    const unsigned short* kro = qc + (size_t)s * QCN + 6656;
    float y1 = b2f(kro[i]), y2 = b2f(kro[32 + i]);
    kr[(size_t)s * 64 + i] = f2b(y1 * c - y2 * sn);
    kr[(size_t)s * 64 + 32 + i] = f2b(y2 * c + y1 * sn);
  }

  // ---- part3: rope_q (1024 items over 256 threads) ----
#pragma unroll
  for (int t = 0; t < 4; ++t) {
    int idx = t * 256 + tid;           // h*32 + i
    int i = idx & 31, hh = idx >> 5;
    float inv = exp2f(-(float)i * 0.4152410118609203f);
    float ang = (float)s * inv;
    float c = cosf(ang), sn = sinf(ang);
    size_t base = (size_t)s * QCN + hh * QH + 128;
    float z1 = b2f(qc[base + i]), z2 = b2f(qc[base + 32 + i]);
    qc[base + i] = f2b(z1 * c - z2 * sn);
    qc[base + 32 + i] = f2b(z2 * c + z1 * sn);
  }
}

// ---- per-head V transpose: vT[h][v][t] = kv[t][h*256+128+v] ----
__global__ __launch_bounds__(256) void tv_k(const unsigned short* __restrict__ kv,
                                            unsigned short* __restrict__ vT) {
  __shared__ unsigned short t[64][66];
  const int t0 = blockIdx.x * 64, v0 = blockIdx.y * 64, h = blockIdx.z;
  const int tid = threadIdx.x;
#pragma unroll
  for (int i = 0; i < 16; ++i) {
    int idx = tid + i * 256;
    int rr = idx >> 6, cc = idx & 63;
    t[rr][cc] = kv[(size_t)(t0 + rr) * KVN + h * 256 + 128 + v0 + cc];
  }
  __syncthreads();
#pragma unroll
  for (int i = 0; i < 16; ++i) {
    int idx = tid + i * 256;
    int cc = idx >> 6, rr = idx & 63;
    vT[((size_t)h * 128 + v0 + cc) * SEQLEN + t0 + rr] = t[rr][cc];
  }
}

// ---- causal flash attention (swapped QK^T, lane-local softmax, T13, cvt_pk) ----
__global__ __launch_bounds__(256) void attn_k(const unsigned short* __restrict__ qc,
                                              const unsigned short* __restrict__ kv,
                                              const unsigned short* __restrict__ kr,
                                              const unsigned short* __restrict__ vT,
                                              unsigned short* __restrict__ ao) {
  __shared__ __align__(16) unsigned short Kt[64 * 192];   // 24 KB
  __shared__ __align__(16) unsigned short Vt[128 * 72];   // 18 KB
  __shared__ __align__(16) unsigned short Pl[4][32 * 72]; // 18 KB (per-wave)

  const int tid = threadIdx.x;
  const int lane = tid & 63;
  const int w = tid >> 6;
  const int l15 = lane & 15, lg = lane >> 4;
  const int sw = l15 & 7;
  const int bid = blockIdx.x;
  const int qt = 15 - (bid >> 5);   // all heads' heavy tiles dispatch first
  const int h = bid & 31;
  const int n_it = 2 * qt + 2;
  const int qrow_base = qt * 128 + w * 32;
  const f32x4 zero4 = {0.f, 0.f, 0.f, 0.f};

  bf16x8 kregs[4], rregs[2], vregs[4];

  auto loadregs = [&](int t0) {
#pragma unroll
    for (int p = 0; p < 4; ++p) {
      int id = tid + p * 256;
      kregs[p] = *(const bf16x8*)&kv[(size_t)(t0 + (id >> 4)) * KVN + h * 256 + (id & 15) * 8];
    }
#pragma unroll
    for (int p = 0; p < 2; ++p) {
      int id = tid + p * 256;
      rregs[p] = *(const bf16x8*)&kr[(size_t)(t0 + (id >> 3)) * 64 + (id & 7) * 8];
    }
#pragma unroll
    for (int p = 0; p < 4; ++p) {
      int id = tid + p * 256;
      vregs[p] = *(const bf16x8*)&vT[((size_t)h * 128 + (id >> 3)) * SEQLEN + t0 + (id & 7) * 8];
    }
  };
  auto writelds = [&]() {
#pragma unroll
    for (int p = 0; p < 4; ++p) {
      int id = tid + p * 256;
      int r = id >> 4, c16 = id & 15;
      *(bf16x8*)&Kt[r * 192 + ((c16 ^ (r & 7)) << 3)] = kregs[p];
    }
#pragma unroll
    for (int p = 0; p < 2; ++p) {
      int id = tid + p * 256;
      int r = id >> 3;
      *(bf16x8*)&Kt[r * 192 + ((16 + ((id & 7) ^ (r & 7))) << 3)] = rregs[p];
    }
#pragma unroll
    for (int p = 0; p < 4; ++p) {
      int id = tid + p * 256;
      *(bf16x8*)&Vt[(id >> 3) * 72 + (id & 7) * 8] = vregs[p];
    }
  };

  // Q fragments (rows m*16+l15, d = c*32 + lg*8); Q pre-scaled by 192^-0.5
  bf16x8 qf[2][6];
#pragma unroll
  for (int m = 0; m < 2; ++m) {
    const size_t qoff = (size_t)(qrow_base + m * 16 + l15) * QCN + (size_t)h * QH + lg * 8;
#pragma unroll
    for (int c = 0; c < 6; ++c) qf[m][c] = *(const bf16x8*)(qc + qoff + c * 32);
  }

  f32x4 o[2][8];
  float m_r[2], s_r[2];
#pragma unroll
  for (int m = 0; m < 2; ++m) {
#pragma unroll
    for (int vt = 0; vt < 8; ++vt) o[m][vt] = zero4;
    m_r[m] = -1e30f; s_r[m] = 0.f;
  }

  loadregs(0);

#pragma unroll 1
  for (int it = 0; it < n_it; ++it) {
    const int t0 = it * 64;
    writelds();
    __syncthreads();
    if (it + 1 < n_it) loadregs((it + 1) * 64);

    // ---- swapped QK^T: lane holds q = m*16+l15, t = tt*16+lg*4+i ----
    f32x4 st[2][4];
    __builtin_amdgcn_s_setprio(1);
#pragma unroll
    for (int tt = 0; tt < 4; ++tt) {
      f32x4 c0 = zero4, c1 = zero4;
      const int krow = (tt * 16 + l15) * 192;
#pragma unroll
      for (int c = 0; c < 6; ++c) {
        bf16x8 kf = *(const bf16x8*)&Kt[krow + (((c * 4 + lg) ^ sw) << 3)];
        c0 = __builtin_amdgcn_mfma_f32_16x16x32_bf16(kf, qf[0][c], c0, 0, 0, 0);
        c1 = __builtin_amdgcn_mfma_f32_16x16x32_bf16(kf, qf[1][c], c1, 0, 0, 0);
      }
      st[0][tt] = c0; st[1][tt] = c1;
    }
    __builtin_amdgcn_s_setprio(0);

    // ---- lane-local online softmax with T13 defer-max ----
    const bool domask = (t0 + 63 > qrow_base);
#pragma unroll
    for (int m = 0; m < 2; ++m) {
      const int qg = qrow_base + m * 16 + l15;
      float mx = -1e30f;
#pragma unroll
      for (int tt = 0; tt < 4; ++tt)
#pragma unroll
        for (int i = 0; i < 4; ++i) {
          float v = st[m][tt][i];
          if (domask) {
            int tg = t0 + tt * 16 + lg * 4 + i;
            v = (tg > qg) ? -1e30f : v;
          }
          st[m][tt][i] = v;
          mx = fmaxf(mx, v);
        }
      mx = fmaxf(mx, __shfl_xor(mx, 16, 64));
      mx = fmaxf(mx, __shfl_xor(mx, 32, 64));
      float mn;
      if (__all(mx - m_r[m] <= 8.f)) {   // defer: keep old max, skip rescale
        mn = m_r[m];
      } else {
        mn = fmaxf(m_r[m], mx);
        float al = __expf(m_r[m] - mn);
        m_r[m] = mn;
        s_r[m] *= al;
#pragma unroll
        for (int vt = 0; vt < 8; ++vt)
#pragma unroll
          for (int i = 0; i < 4; ++i) o[m][vt][i] *= al;
      }
      float ps = 0.f;
#pragma unroll
      for (int tt = 0; tt < 4; ++tt)
#pragma unroll
        for (int i = 0; i < 4; ++i) {
          float p = __expf(st[m][tt][i] - mn);
          st[m][tt][i] = p;
          ps += p;
        }
      ps += __shfl_xor(ps, 16, 64);
      ps += __shfl_xor(ps, 32, 64);
      s_r[m] += ps;

      // packed P write via v_cvt_pk_bf16_f32 (RNE, 2 f32 -> 1 u32)
#pragma unroll
      for (int tt = 0; tt < 4; ++tt) {
        unsigned int r0, r1;
        asm("v_cvt_pk_bf16_f32 %0, %1, %2" : "=v"(r0) : "v"(st[m][tt][0]), "v"(st[m][tt][1]));
        asm("v_cvt_pk_bf16_f32 %0, %1, %2" : "=v"(r1) : "v"(st[m][tt][2]), "v"(st[m][tt][3]));
        uint2 pk; pk.x = r0; pk.y = r1;
        *(uint2*)&Pl[w][(m * 16 + l15) * 72 + tt * 16 + lg * 4] = pk;
      }
    }

    // ---- swapped PV: O^T[v][q] ----
    bf16x8 pa[2][2];
#pragma unroll
    for (int m = 0; m < 2; ++m)
#pragma unroll
      for (int ks = 0; ks < 2; ++ks)
        pa[m][ks] = *(const bf16x8*)&Pl[w][(m * 16 + l15) * 72 + ks * 32 + lg * 8];
    __builtin_amdgcn_s_setprio(1);
#pragma unroll
    for (int vt = 0; vt < 8; ++vt) {
      bf16x8 b0 = *(const bf16x8*)&Vt[(vt * 16 + l15) * 72 + lg * 8];
      bf16x8 b1 = *(const bf16x8*)&Vt[(vt * 16 + l15) * 72 + 32 + lg * 8];
#pragma unroll
      for (int m = 0; m < 2; ++m) {
        o[m][vt] = __builtin_amdgcn_mfma_f32_16x16x32_bf16(b0, pa[m][0], o[m][vt], 0, 0, 0);
        o[m][vt] = __builtin_amdgcn_mfma_f32_16x16x32_bf16(b1, pa[m][1], o[m][vt], 0, 0, 0);
      }
    }
    __builtin_amdgcn_s_setprio(0);
    __syncthreads();
  }

  // ---- normalize + packed store ----
#pragma unroll
  for (int m = 0; m < 2; ++m) {
    float rs = 1.f / s_r[m];
    int qg = qrow_base + m * 16 + l15;
#pragma unroll
    for (int vt = 0; vt < 8; ++vt) {
      ushort4 pk;
      pk.x = f2b(o[m][vt][0] * rs); pk.y = f2b(o[m][vt][1] * rs);
      pk.z = f2b(o[m][vt][2] * rs); pk.w = f2b(o[m][vt][3] * rs);
      *(ushort4*)&ao[(size_t)qg * (NH * 128) + h * 128 + vt * 16 + lg * 4] = pk;
    }
  }
}

extern "C" void kernel_launch(void* const* d_in, const int* in_sizes, int n_in,
                              void* d_out, int out_size, void* d_ws, size_t ws_size,
                              hipStream_t stream) {
  (void)in_sizes; (void)n_in; (void)out_size; (void)ws_size;
  const float* hs = (const float*)d_in[1];
  const float* Wq = (const float*)d_in[2];
  const float* Wkva = (const float*)d_in[3];
  const float* lnw = (const float*)d_in[4];
  const float* Wkvb = (const float*)d_in[5];
  const float* Wo = (const float*)d_in[6];
  float* out = (float*)d_out;
  char* ws = (char*)d_ws;

  constexpr size_t OFF_HSBF = 0;                                    // 2048x4096 bf16
  constexpr size_t OFF_WQT = OFF_HSBF + (size_t)2048 * 4096 * 2;    // 6144x4096 bf16
  constexpr size_t OFF_WKVAT = OFF_WQT + (size_t)6144 * 4096 * 2;   // 640x4096 bf16 (contiguous -> combined B)
  constexpr size_t OFF_WKVBT = OFF_WKVAT + (size_t)640 * 4096 * 2;  // 8192x512 bf16 (pads combined B rows)
  constexpr size_t OFF_WOT = OFF_WKVBT + (size_t)8192 * 512 * 2;    // 4096x4096 bf16
  constexpr size_t OFF_QC = OFF_WOT + (size_t)4096 * 4096 * 2;      // 2048x6912 bf16 (q | ckv)
  constexpr size_t OFF_CKVN = OFF_QC + (size_t)2048 * 6912 * 2;     // 2048x512 bf16
  constexpr size_t OFF_KR = OFF_CKVN + (size_t)2048 * 512 * 2;      // 2048x64 bf16
  constexpr size_t OFF_KV = OFF_KR + (size_t)2048 * 64 * 2;         // 2048x8192 bf16
  constexpr size_t OFF_VT = OFF_KV + (size_t)2048 * 8192 * 2;       // 32x128x2048 bf16
  constexpr size_t OFF_AO = OFF_VT + (size_t)32 * 128 * 2048 * 2;   // 2048x4096 bf16

  unsigned short* hs_bf = (unsigned short*)(ws + OFF_HSBF);
  unsigned short* WqT = (unsigned short*)(ws + OFF_WQT);
  unsigned short* WkvaT = (unsigned short*)(ws + OFF_WKVAT);
  unsigned short* WkvbT = (unsigned short*)(ws + OFF_WKVBT);
  unsigned short* WoT = (unsigned short*)(ws + OFF_WOT);
  unsigned short* qcbuf = (unsigned short*)(ws + OFF_QC);
  unsigned short* ckvn = (unsigned short*)(ws + OFF_CKVN);
  unsigned short* kr = (unsigned short*)(ws + OFF_KR);
  unsigned short* kvbuf = (unsigned short*)(ws + OFF_KV);
  unsigned short* vT = (unsigned short*)(ws + OFF_VT);
  unsigned short* ao = (unsigned short*)(ws + OFF_AO);

  convk<<<dim3(8192), 256, 0, stream>>>(hs, hs_bf, 2048 * 4096 / 4);
  // Wq pre-scaled by 192^-0.5 (commutes with RoPE; attn drops the scale mul)
  tconv<<<dim3(64, 96), 256, 0, stream>>>(Wq, WqT, 4096, 6144, 6144, 0.07216878364870323f);
  tconv<<<dim3(64, 10), 256, 0, stream>>>(Wkva, WkvaT, 4096, 576, 640, 1.f);
  tconv<<<dim3(8, 128), 256, 0, stream>>>(Wkvb, WkvbT, 512, 8192, 8192, 1.f);
  tconv<<<dim3(64, 64), 256, 0, stream>>>(Wo, WoT, 4096, 4096, 4096, 1.f);

  // combined q|ckv GEMM: B = [WqT; WkvaT(+pad)], N = 6912 -> 216 blocks
  gemm8p<256, unsigned short><<<dim3(8 * 27), 512, 0, stream>>>(hs_bf, WqT, qcbuf, 2048, QCN, 4096);
  normrope_k<<<dim3(2048), 256, 0, stream>>>(qcbuf, lnw, ckvn, kr);
  gemm8p<256, unsigned short><<<dim3(8 * 32), 512, 0, stream>>>(ckvn, WkvbT, kvbuf, 2048, 8192, 512);
  tv_k<<<dim3(32, 2, 32), 256, 0, stream>>>(kvbuf, vT);
  attn_k<<<dim3(512), 256, 0, stream>>>(qcbuf, kvbuf, kr, vT, ao);
  gemm8p<128, float><<<dim3(16 * 16), 512, 0, stream>>>(ao, WoT, out, 2048, 4096, 4096);
}

// Round 19
// 438.590 us; speedup vs baseline: 1.0175x; 1.0175x over previous
//
#include <hip/hip_runtime.h>

// ---------------------------------------------------------------------------
// Kimi MLA attention block, MI355X (gfx950).  Round 19 = round-18 (446us) +
// tv_k fused into the kvb GEMM epilogue (SPLITV): V-half columns are written
// directly in transposed vT[h*128+v][t] layout as packed ushort4 (each lane
// holds 4 consecutive t for one v); K-half columns written normally.
// Deletes 32MB of HBM traffic (kvbuf V-write + tv_k read) + one launch.
// gemm8p schedule/LDS/math byte-identical to the proven r13 configuration.
// ---------------------------------------------------------------------------

typedef __bf16 bf16x8 __attribute__((ext_vector_type(8)));
typedef float f32x4 __attribute__((ext_vector_type(4)));

#define SEQLEN 2048
#define NH 32
#define QH 192
#define QCN 6912  // combined q (6144) + ckv (640 used, 768 padded) columns
#define KVN 8192  // NH*256
#define HID 4096

#define AS1 __attribute__((address_space(1)))
#define AS3 __attribute__((address_space(3)))

__device__ __forceinline__ unsigned short f2b(float f) {
  union { float f; unsigned int u; } x; x.f = f;
  unsigned int r = (x.u + 0x7FFFu + ((x.u >> 16) & 1u)) >> 16;
  return (unsigned short)r;
}
__device__ __forceinline__ float b2f(unsigned short b) {
  union { unsigned int u; float f; } x; x.u = ((unsigned int)b) << 16;
  return x.f;
}

// ---- elementwise f32 -> bf16 (vectorized) ----
__global__ __launch_bounds__(256) void convk(const float* __restrict__ in,
                                             unsigned short* __restrict__ out,
                                             int n4) {
  int i = blockIdx.x * 256 + threadIdx.x;
  if (i < n4) {
    float4 v = ((const float4*)in)[i];
    ushort4 o;
    o.x = f2b(v.x); o.y = f2b(v.y); o.z = f2b(v.z); o.w = f2b(v.w);
    ((ushort4*)out)[i] = o;
  }
}

// ---- transpose+convert+scale: out[c][r] = bf16(scl*in[r][c]) ----
__global__ __launch_bounds__(256) void tconv(const float* __restrict__ in,
                                             unsigned short* __restrict__ out,
                                             int R, int Cin, int Cp, float scl) {
  __shared__ float t[64][65];
  const int r0 = blockIdx.x * 64, c0 = blockIdx.y * 64;
  const int tid = threadIdx.x;
#pragma unroll
  for (int i = 0; i < 16; ++i) {
    int idx = tid + i * 256;
    int rr = idx >> 6, cc = idx & 63;
    int c = c0 + cc;
    t[rr][cc] = (c < Cin) ? in[(size_t)(r0 + rr) * Cin + c] * scl : 0.f;
  }
  __syncthreads();
#pragma unroll
  for (int i = 0; i < 16; ++i) {
    int idx = tid + i * 256;
    int cc = idx >> 6, rr = idx & 63;
    out[(size_t)(c0 + cc) * R + (r0 + rr)] = f2b(t[rr][cc]);
  }
}

// ---- MFMA quadrant helper (all register indices compile-time; rule #20) ----
template <int MH, int MHALF, int PAIR>
__device__ __forceinline__ void mmaq(f32x4 (*acc)[4], const bf16x8* aR, const bf16x8* bX) {
  __builtin_amdgcn_s_setprio(1);
#pragma unroll
  for (int i2 = 0; i2 < MH; ++i2)
#pragma unroll
    for (int kk = 0; kk < 2; ++kk)
#pragma unroll
      for (int j = 0; j < 2; ++j)
        acc[MHALF * MH + i2][PAIR * 2 + j] = __builtin_amdgcn_mfma_f32_16x16x32_bf16(
            aR[i2 * 2 + kk], bX[j * 2 + kk], acc[MHALF * MH + i2][PAIR * 2 + j], 0, 0, 0);
  __builtin_amdgcn_s_setprio(0);
}

#define PH_SYNC()                                        \
  __builtin_amdgcn_s_barrier();                          \
  asm volatile("s_waitcnt lgkmcnt(0)" ::: "memory");     \
  __builtin_amdgcn_sched_barrier(0)
#define PH_END() __builtin_amdgcn_s_barrier()

// ---- BMx256 8-phase GEMM: C[M,N] = A[M,K] * B[N,K]^T, bf16 in, fp32 acc ----
// LDS half-tile = [rows][64] bf16 row-major, slot-XOR: unit u holds
// G[row = u>>3][slot = (u&7) ^ ((u>>3)&7)]. Staging covers whole 128B rows
// (coalesced); frag read slot = (kk*4+(l>>4)) ^ (l&7) (conflict-free).
// 8-phase schedule, counted vmcnt(4) at p4/p8, two barriers/phase. [r13]
// SPLITV (kvb only): per-head cols 0..127 -> C normal; cols 128..255 ->
// VT[h*128+(ch-128)][r..r+3] packed ushort4 (fused V transpose).
template <int BM, typename OutT, bool SPLITV = false>
__global__ __launch_bounds__(512, 2) void gemm8p(const unsigned short* __restrict__ A,
                                                 const unsigned short* __restrict__ B,
                                                 OutT* __restrict__ C,
                                                 int M, int N, int K,
                                                 unsigned short* __restrict__ VT) {
  constexpr int MF = BM / 32;
  constexpr int MH = MF / 2;
  constexpr int ARND = BM / 128;
  __shared__ __align__(16) unsigned short As[2][2][BM * 32];  // [buf][half]
  __shared__ __align__(16) unsigned short Bs[2][2][8192];

  const int tid = threadIdx.x;
  const int lane = tid & 63;
  const int w = tid >> 6;
  const int wr = w >> 2, wc = w & 3;
  const int l15 = lane & 15, lg = lane >> 4;
  const int l7 = lane & 7;
  const int ntn = N >> 8;
  // XCD-row swizzle (bijective for nbm % 8 == 0; here nbm in {8,16})
  const int g = blockIdx.x & 7, s = blockIdx.x >> 3;
  const int bn = s % ntn;
  const int bm = g + 8 * (s / ntn);
  const int m0 = bm * BM, n0 = bn << 8;

  auto stA = [&](int t, int h) {
    const int buf = t & 1, k0 = t << 6;
#pragma unroll
    for (int r = 0; r < ARND; ++r) {
      int u = r * 512 + tid;
      int row = u >> 3;
      int sslot = (u & 7) ^ (row & 7);
      __builtin_amdgcn_global_load_lds(
          (const AS1 void*)(A + (size_t)(m0 + h * (BM / 2) + row) * K + (k0 + sslot * 8)),
          (AS3 void*)(&As[buf][h][u * 8]), 16, 0, 0);
    }
  };
  auto stB = [&](int t, int h) {
    const int buf = t & 1, k0 = t << 6;
#pragma unroll
    for (int r = 0; r < 2; ++r) {
      int u = r * 512 + tid;
      int row = u >> 3;
      int sslot = (u & 7) ^ (row & 7);
      __builtin_amdgcn_global_load_lds(
          (const AS1 void*)(B + (size_t)(n0 + h * 128 + row) * K + (k0 + sslot * 8)),
          (AS3 void*)(&Bs[buf][h][u * 8]), 16, 0, 0);
    }
  };

  const f32x4 zero4 = {0.f, 0.f, 0.f, 0.f};
  f32x4 acc[MF][4];
#pragma unroll
  for (int i = 0; i < MF; ++i)
#pragma unroll
    for (int j = 0; j < 4; ++j) acc[i][j] = zero4;

  bf16x8 aR[MF], bA[4], bB[4];
  auto ldA = [&](int buf, int mhalf) {
#pragma unroll
    for (int i2 = 0; i2 < MH; ++i2)
#pragma unroll
      for (int kk = 0; kk < 2; ++kk) {
        int row = (mhalf * MH + i2) * 16 + l15;
        int slot = (kk * 4 + lg) ^ l7;
        aR[i2 * 2 + kk] = *(const bf16x8*)&As[buf][wr][(row * 8 + slot) * 8];
      }
  };
  auto ldB = [&](int buf, int pair, bf16x8* dst) {
#pragma unroll
    for (int j = 0; j < 2; ++j)
#pragma unroll
      for (int kk = 0; kk < 2; ++kk) {
        int row = (wc & 1) * 64 + (pair * 2 + j) * 16 + l15;
        int slot = (kk * 4 + lg) ^ l7;
        dst[j * 2 + kk] = *(const bf16x8*)&Bs[buf][wc >> 1][(row * 8 + slot) * 8];
      }
  };

  const int nk = K >> 6;
  const int ni = nk >> 1;

  stA(0, 0); stA(0, 1); stB(0, 0); stB(0, 1);
  stB(1, 0); stB(1, 1);
  asm volatile("s_waitcnt vmcnt(4)" ::: "memory");
  __builtin_amdgcn_s_barrier();

#pragma unroll 1
  for (int i = 0; i < ni; ++i) {
    const int tO = 2 * i + 1, tN = 2 * i + 2, tN1 = 2 * i + 3;
    const bool pfN = tN < nk, pfN1 = tN1 < nk;
    const bool steady = (i + 1 < ni);
    ldA(0, 0); ldB(0, 0, bA); stA(tO, 0);
    PH_SYNC(); mmaq<MH, 0, 0>(acc, aR, bA); PH_END();
    ldB(0, 1, bB); stA(tO, 1);
    PH_SYNC(); mmaq<MH, 0, 1>(acc, aR, bB); PH_END();
    ldA(0, 1); if (pfN) stB(tN, 0);
    PH_SYNC(); mmaq<MH, 1, 1>(acc, aR, bB); PH_END();
    if (pfN) stB(tN, 1);
    if (steady) { asm volatile("s_waitcnt vmcnt(4)" ::: "memory"); }
    else        { asm volatile("s_waitcnt vmcnt(0)" ::: "memory"); }
    PH_SYNC(); mmaq<MH, 1, 0>(acc, aR, bA); PH_END();
    ldA(1, 0); ldB(1, 0, bA); if (pfN) stA(tN, 0);
    PH_SYNC(); mmaq<MH, 0, 0>(acc, aR, bA); PH_END();
    ldB(1, 1, bB); if (pfN) stA(tN, 1);
    PH_SYNC(); mmaq<MH, 0, 1>(acc, aR, bB); PH_END();
    ldA(1, 1); if (pfN1) stB(tN1, 0);
    PH_SYNC(); mmaq<MH, 1, 1>(acc, aR, bB); PH_END();
    if (pfN1) stB(tN1, 1);
    if (steady) { asm volatile("s_waitcnt vmcnt(4)" ::: "memory"); }
    else        { asm volatile("s_waitcnt vmcnt(0)" ::: "memory"); }
    PH_SYNC(); mmaq<MH, 1, 0>(acc, aR, bA); PH_END();
  }

  const int r0 = m0 + wr * (BM / 2), c0 = n0 + wc * 64;
#pragma unroll
  for (int mf = 0; mf < MF; ++mf)
#pragma unroll
    for (int nf = 0; nf < 4; ++nf) {
      int r = r0 + mf * 16 + lg * 4;
      int c = c0 + nf * 16 + l15;
      if constexpr (SPLITV) {
        // branch is wave-uniform: (c&255)<128 decided by wc (wave) and nf (unrolled)
        int head = c >> 8, ch = c & 255;
        if (ch < 128) {
#pragma unroll
          for (int i = 0; i < 4; ++i)
            ((unsigned short*)C)[(size_t)(r + i) * N + c] = f2b(acc[mf][nf][i]);
        } else {
          ushort4 pk;
          pk.x = f2b(acc[mf][nf][0]); pk.y = f2b(acc[mf][nf][1]);
          pk.z = f2b(acc[mf][nf][2]); pk.w = f2b(acc[mf][nf][3]);
          *(ushort4*)&VT[((size_t)head * 128 + (ch - 128)) * SEQLEN + r] = pk;
        }
      } else {
#pragma unroll
        for (int i = 0; i < 4; ++i) {
          float v = acc[mf][nf][i];
          if constexpr (sizeof(OutT) == 2)
            ((unsigned short*)C)[(size_t)(r + i) * N + c] = f2b(v);
          else
            ((float*)C)[(size_t)(r + i) * N + c] = v;
        }
      }
    }
}

// ---- fused rmsnorm + rope_k + rope_q, one block per sequence row s ----
__global__ __launch_bounds__(256) void normrope_k(unsigned short* __restrict__ qc,
                                                  const float* __restrict__ w,
                                                  unsigned short* __restrict__ ckvn,
                                                  unsigned short* __restrict__ kr) {
  const int s = blockIdx.x;
  const int tid = threadIdx.x;
  // ---- part1: rmsnorm qc[s][6144..6655] -> ckvn ----
  const unsigned short* row = qc + (size_t)s * QCN + 6144;
  float x0 = b2f(row[tid]), x1 = b2f(row[tid + 256]);
  float ss = x0 * x0 + x1 * x1;
#pragma unroll
  for (int o = 1; o < 64; o <<= 1) ss += __shfl_xor(ss, o, 64);
  __shared__ float red[4];
  if ((tid & 63) == 0) red[tid >> 6] = ss;
  __syncthreads();
  float rs = rsqrtf((red[0] + red[1] + red[2] + red[3]) * (1.f / 512.f) + 1e-6f);
  ckvn[(size_t)s * 512 + tid] = f2b(w[tid] * x0 * rs);
  ckvn[(size_t)s * 512 + tid + 256] = f2b(w[tid + 256] * x1 * rs);

  // ---- part2: rope_k qc[s][6656..6719] -> kr ----
  if (tid < 32) {
    int i = tid;
    float inv = exp2f(-(float)i * 0.4152410118609203f);
    float ang = (float)s * inv;
    float c = cosf(ang), sn = sinf(ang);
    const unsigned short* kro = qc + (size_t)s * QCN + 6656;
    float y1 = b2f(kro[i]), y2 = b2f(kro[32 + i]);
    kr[(size_t)s * 64 + i] = f2b(y1 * c - y2 * sn);
    kr[(size_t)s * 64 + 32 + i] = f2b(y2 * c + y1 * sn);
  }

  // ---- part3: rope_q in place, qc[s][h*192+128..191] ----
#pragma unroll
  for (int t = 0; t < 4; ++t) {
    int idx = t * 256 + tid;           // h*32 + i
    int i = idx & 31, hh = idx >> 5;
    float inv = exp2f(-(float)i * 0.4152410118609203f);
    float ang = (float)s * inv;
    float c = cosf(ang), sn = sinf(ang);
    size_t base = (size_t)s * QCN + hh * QH + 128;
    float z1 = b2f(qc[base + i]), z2 = b2f(qc[base + 32 + i]);
    qc[base + i] = f2b(z1 * c - z2 * sn);
    qc[base + 32 + i] = f2b(z2 * c + z1 * sn);
  }
}

// ---- causal flash attention (swapped QK^T, lane-local softmax, T13, cvt_pk) ----
__global__ __launch_bounds__(256) void attn_k(const unsigned short* __restrict__ qc,
                                              const unsigned short* __restrict__ kv,
                                              const unsigned short* __restrict__ kr,
                                              const unsigned short* __restrict__ vT,
                                              unsigned short* __restrict__ ao) {
  __shared__ __align__(16) unsigned short Kt[64 * 192];   // 24 KB
  __shared__ __align__(16) unsigned short Vt[128 * 72];   // 18 KB
  __shared__ __align__(16) unsigned short Pl[4][32 * 72]; // 18 KB (per-wave)

  const int tid = threadIdx.x;
  const int lane = tid & 63;
  const int w = tid >> 6;
  const int l15 = lane & 15, lg = lane >> 4;
  const int sw = l15 & 7;
  const int bid = blockIdx.x;
  const int qt = 15 - (bid >> 5);   // all heads' heavy tiles dispatch first
  const int h = bid & 31;
  const int n_it = 2 * qt + 2;
  const int qrow_base = qt * 128 + w * 32;
  const f32x4 zero4 = {0.f, 0.f, 0.f, 0.f};

  bf16x8 kregs[4], rregs[2], vregs[4];

  auto loadregs = [&](int t0) {
#pragma unroll
    for (int p = 0; p < 4; ++p) {
      int id = tid + p * 256;
      kregs[p] = *(const bf16x8*)&kv[(size_t)(t0 + (id >> 4)) * KVN + h * 256 + (id & 15) * 8];
    }
#pragma unroll
    for (int p = 0; p < 2; ++p) {
      int id = tid + p * 256;
      rregs[p] = *(const bf16x8*)&kr[(size_t)(t0 + (id >> 3)) * 64 + (id & 7) * 8];
    }
#pragma unroll
    for (int p = 0; p < 4; ++p) {
      int id = tid + p * 256;
      vregs[p] = *(const bf16x8*)&vT[((size_t)h * 128 + (id >> 3)) * SEQLEN + t0 + (id & 7) * 8];
    }
  };
  auto writelds = [&]() {
#pragma unroll
    for (int p = 0; p < 4; ++p) {
      int id = tid + p * 256;
      int r = id >> 4, c16 = id & 15;
      *(bf16x8*)&Kt[r * 192 + ((c16 ^ (r & 7)) << 3)] = kregs[p];
    }
#pragma unroll
    for (int p = 0; p < 2; ++p) {
      int id = tid + p * 256;
      int r = id >> 3;
      *(bf16x8*)&Kt[r * 192 + ((16 + ((id & 7) ^ (r & 7))) << 3)] = rregs[p];
    }
#pragma unroll
    for (int p = 0; p < 4; ++p) {
      int id = tid + p * 256;
      *(bf16x8*)&Vt[(id >> 3) * 72 + (id & 7) * 8] = vregs[p];
    }
  };

  // Q fragments (rows m*16+l15, d = c*32 + lg*8); Q pre-scaled by 192^-0.5
  bf16x8 qf[2][6];
#pragma unroll
  for (int m = 0; m < 2; ++m) {
    const size_t qoff = (size_t)(qrow_base + m * 16 + l15) * QCN + (size_t)h * QH + lg * 8;
#pragma unroll
    for (int c = 0; c < 6; ++c) qf[m][c] = *(const bf16x8*)(qc + qoff + c * 32);
  }

  f32x4 o[2][8];
  float m_r[2], s_r[2];
#pragma unroll
  for (int m = 0; m < 2; ++m) {
#pragma unroll
    for (int vt = 0; vt < 8; ++vt) o[m][vt] = zero4;
    m_r[m] = -1e30f; s_r[m] = 0.f;
  }

  loadregs(0);

#pragma unroll 1
  for (int it = 0; it < n_it; ++it) {
    const int t0 = it * 64;
    writelds();
    __syncthreads();
    if (it + 1 < n_it) loadregs((it + 1) * 64);

    // ---- swapped QK^T: lane holds q = m*16+l15, t = tt*16+lg*4+i ----
    f32x4 st[2][4];
    __builtin_amdgcn_s_setprio(1);
#pragma unroll
    for (int tt = 0; tt < 4; ++tt) {
      f32x4 c0 = zero4, c1 = zero4;
      const int krow = (tt * 16 + l15) * 192;
#pragma unroll
      for (int c = 0; c < 6; ++c) {
        bf16x8 kf = *(const bf16x8*)&Kt[krow + (((c * 4 + lg) ^ sw) << 3)];
        c0 = __builtin_amdgcn_mfma_f32_16x16x32_bf16(kf, qf[0][c], c0, 0, 0, 0);
        c1 = __builtin_amdgcn_mfma_f32_16x16x32_bf16(kf, qf[1][c], c1, 0, 0, 0);
      }
      st[0][tt] = c0; st[1][tt] = c1;
    }
    __builtin_amdgcn_s_setprio(0);

    // ---- lane-local online softmax with T13 defer-max ----
    const bool domask = (t0 + 63 > qrow_base);
#pragma unroll
    for (int m = 0; m < 2; ++m) {
      const int qg = qrow_base + m * 16 + l15;
      float mx = -1e30f;
#pragma unroll
      for (int tt = 0; tt < 4; ++tt)
#pragma unroll
        for (int i = 0; i < 4; ++i) {
          float v = st[m][tt][i];
          if (domask) {
            int tg = t0 + tt * 16 + lg * 4 + i;
            v = (tg > qg) ? -1e30f : v;
          }
          st[m][tt][i] = v;
          mx = fmaxf(mx, v);
        }
      mx = fmaxf(mx, __shfl_xor(mx, 16, 64));
      mx = fmaxf(mx, __shfl_xor(mx, 32, 64));
      float mn;
      if (__all(mx - m_r[m] <= 8.f)) {   // defer: keep old max, skip rescale
        mn = m_r[m];
      } else {
        mn = fmaxf(m_r[m], mx);
        float al = __expf(m_r[m] - mn);
        m_r[m] = mn;
        s_r[m] *= al;
#pragma unroll
        for (int vt = 0; vt < 8; ++vt)
#pragma unroll
          for (int i = 0; i < 4; ++i) o[m][vt][i] *= al;
      }
      float ps = 0.f;
#pragma unroll
      for (int tt = 0; tt < 4; ++tt)
#pragma unroll
        for (int i = 0; i < 4; ++i) {
          float p = __expf(st[m][tt][i] - mn);
          st[m][tt][i] = p;
          ps += p;
        }
      ps += __shfl_xor(ps, 16, 64);
      ps += __shfl_xor(ps, 32, 64);
      s_r[m] += ps;

      // packed P write via v_cvt_pk_bf16_f32 (RNE, 2 f32 -> 1 u32)
#pragma unroll
      for (int tt = 0; tt < 4; ++tt) {
        unsigned int r0, r1;
        asm("v_cvt_pk_bf16_f32 %0, %1, %2" : "=v"(r0) : "v"(st[m][tt][0]), "v"(st[m][tt][1]));
        asm("v_cvt_pk_bf16_f32 %0, %1, %2" : "=v"(r1) : "v"(st[m][tt][2]), "v"(st[m][tt][3]));
        uint2 pk; pk.x = r0; pk.y = r1;
        *(uint2*)&Pl[w][(m * 16 + l15) * 72 + tt * 16 + lg * 4] = pk;
      }
    }

    // ---- swapped PV: O^T[v][q] ----
    bf16x8 pa[2][2];
#pragma unroll
    for (int m = 0; m < 2; ++m)
#pragma unroll
      for (int ks = 0; ks < 2; ++ks)
        pa[m][ks] = *(const bf16x8*)&Pl[w][(m * 16 + l15) * 72 + ks * 32 + lg * 8];
    __builtin_amdgcn_s_setprio(1);
#pragma unroll
    for (int vt = 0; vt < 8; ++vt) {
      bf16x8 b0 = *(const bf16x8*)&Vt[(vt * 16 + l15) * 72 + lg * 8];
      bf16x8 b1 = *(const bf16x8*)&Vt[(vt * 16 + l15) * 72 + 32 + lg * 8];
#pragma unroll
      for (int m = 0; m < 2; ++m) {
        o[m][vt] = __builtin_amdgcn_mfma_f32_16x16x32_bf16(b0, pa[m][0], o[m][vt], 0, 0, 0);
        o[m][vt] = __builtin_amdgcn_mfma_f32_16x16x32_bf16(b1, pa[m][1], o[m][vt], 0, 0, 0);
      }
    }
    __builtin_amdgcn_s_setprio(0);
    __syncthreads();
  }

  // ---- normalize + packed store ----
#pragma unroll
  for (int m = 0; m < 2; ++m) {
    float rs = 1.f / s_r[m];
    int qg = qrow_base + m * 16 + l15;
#pragma unroll
    for (int vt = 0; vt < 8; ++vt) {
      ushort4 pk;
      pk.x = f2b(o[m][vt][0] * rs); pk.y = f2b(o[m][vt][1] * rs);
      pk.z = f2b(o[m][vt][2] * rs); pk.w = f2b(o[m][vt][3] * rs);
      *(ushort4*)&ao[(size_t)qg * (NH * 128) + h * 128 + vt * 16 + lg * 4] = pk;
    }
  }
}

extern "C" void kernel_launch(void* const* d_in, const int* in_sizes, int n_in,
                              void* d_out, int out_size, void* d_ws, size_t ws_size,
                              hipStream_t stream) {
  (void)in_sizes; (void)n_in; (void)out_size; (void)ws_size;
  const float* hs = (const float*)d_in[1];
  const float* Wq = (const float*)d_in[2];
  const float* Wkva = (const float*)d_in[3];
  const float* lnw = (const float*)d_in[4];
  const float* Wkvb = (const float*)d_in[5];
  const float* Wo = (const float*)d_in[6];
  float* out = (float*)d_out;
  char* ws = (char*)d_ws;

  constexpr size_t OFF_HSBF = 0;                                    // 2048x4096 bf16
  constexpr size_t OFF_WQT = OFF_HSBF + (size_t)2048 * 4096 * 2;    // 6144x4096 bf16
  constexpr size_t OFF_WKVAT = OFF_WQT + (size_t)6144 * 4096 * 2;   // 640x4096 bf16 (contiguous -> combined B)
  constexpr size_t OFF_WKVBT = OFF_WKVAT + (size_t)640 * 4096 * 2;  // 8192x512 bf16 (pads combined B rows)
  constexpr size_t OFF_WOT = OFF_WKVBT + (size_t)8192 * 512 * 2;    // 4096x4096 bf16
  constexpr size_t OFF_QC = OFF_WOT + (size_t)4096 * 4096 * 2;      // 2048x6912 bf16 (q | ckv)
  constexpr size_t OFF_CKVN = OFF_QC + (size_t)2048 * 6912 * 2;     // 2048x512 bf16
  constexpr size_t OFF_KR = OFF_CKVN + (size_t)2048 * 512 * 2;      // 2048x64 bf16
  constexpr size_t OFF_KV = OFF_KR + (size_t)2048 * 64 * 2;         // 2048x8192 bf16
  constexpr size_t OFF_VT = OFF_KV + (size_t)2048 * 8192 * 2;       // 32x128x2048 bf16
  constexpr size_t OFF_AO = OFF_VT + (size_t)32 * 128 * 2048 * 2;   // 2048x4096 bf16

  unsigned short* hs_bf = (unsigned short*)(ws + OFF_HSBF);
  unsigned short* WqT = (unsigned short*)(ws + OFF_WQT);
  unsigned short* WkvaT = (unsigned short*)(ws + OFF_WKVAT);
  unsigned short* WkvbT = (unsigned short*)(ws + OFF_WKVBT);
  unsigned short* WoT = (unsigned short*)(ws + OFF_WOT);
  unsigned short* qcbuf = (unsigned short*)(ws + OFF_QC);
  unsigned short* ckvn = (unsigned short*)(ws + OFF_CKVN);
  unsigned short* kr = (unsigned short*)(ws + OFF_KR);
  unsigned short* kvbuf = (unsigned short*)(ws + OFF_KV);
  unsigned short* vT = (unsigned short*)(ws + OFF_VT);
  unsigned short* ao = (unsigned short*)(ws + OFF_AO);

  convk<<<dim3(8192), 256, 0, stream>>>(hs, hs_bf, 2048 * 4096 / 4);
  // Wq pre-scaled by 192^-0.5 (commutes with RoPE; attn drops the scale mul)
  tconv<<<dim3(64, 96), 256, 0, stream>>>(Wq, WqT, 4096, 6144, 6144, 0.07216878364870323f);
  tconv<<<dim3(64, 10), 256, 0, stream>>>(Wkva, WkvaT, 4096, 576, 640, 1.f);
  tconv<<<dim3(8, 128), 256, 0, stream>>>(Wkvb, WkvbT, 512, 8192, 8192, 1.f);
  tconv<<<dim3(64, 64), 256, 0, stream>>>(Wo, WoT, 4096, 4096, 4096, 1.f);

  // combined q|ckv GEMM: B = [WqT; WkvaT(+pad)], N = 6912 -> 216 blocks
  gemm8p<256, unsigned short><<<dim3(8 * 27), 512, 0, stream>>>(hs_bf, WqT, qcbuf, 2048, QCN, 4096, nullptr);
  normrope_k<<<dim3(2048), 256, 0, stream>>>(qcbuf, lnw, ckvn, kr);
  // kvb GEMM with fused V transpose: K-half -> kvbuf, V-half -> vT
  gemm8p<256, unsigned short, true><<<dim3(8 * 32), 512, 0, stream>>>(ckvn, WkvbT, kvbuf, 2048, 8192, 512, vT);
  attn_k<<<dim3(512), 256, 0, stream>>>(qcbuf, kvbuf, kr, vT, ao);
  gemm8p<128, float><<<dim3(16 * 16), 512, 0, stream>>>(ao, WoT, out, 2048, 4096, 4096, nullptr);
}